// Round 10
// baseline (102.659 us; speedup 1.0000x reference)
//
#include <hip/hip_runtime.h>

#define C_    64
#define H_    40
#define W_    40
#define KS    11
#define HP    30          // H_ - KS + 1
#define NB    4
#define NL    900         // HP*HP
#define ND    59          // 2*(HP-1)+1
#define EPSF  1e-4f
#define PCH   6           // output rows per chunk (fallback path)
#define PCHB  10          // output rows per chunk (main box path)
#define NCHB  3           // ceil(HP/PCHB)
#define NPLMAX (PCHB + KS - 1)   // 20 planes resident in LDS
#define SCW   65          // fallback scratch row stride (odd -> conflict-free)
#define NINF  -3.4e38f
#define MPAD  1664        // 13*128, padded M=N (packed staging only)
#define GBLK  1600        // elements per 40x40 G block (f16)
#define GBATCH (1600 * 1600)   // elements of Gt per batch
#define GSTEPT 65600      // 41*1600: plane-to-plane step along the dy diagonal
#define TOTALB (NCHB * ND * NB)  // 708 box blocks (incl. early-outs)

typedef _Float16 f16x8 __attribute__((ext_vector_type(8)));
typedef float    f32x4 __attribute__((ext_vector_type(4)));

// ===========================================================================
// k_pack: fp32 images -> f16 octet-packed packed[img][b][oct][MPAD][8].
//         grid (13, NB, 2) x 128 threads; fully coalesced. img==1 also writes
//         per-pixel channel sum-of-squares; img==0 zeroes keys + done-counter.
// ===========================================================================
__global__ __launch_bounds__(128)
void k_pack(const float* __restrict__ im2, const float* __restrict__ im1,
            _Float16* __restrict__ packed, float* __restrict__ ssqbuf,
            unsigned int* __restrict__ keys, unsigned int* __restrict__ counter) {
    const int blk = blockIdx.x, b = blockIdx.y, img = blockIdx.z;
    const int pos = blk * 128 + threadIdx.x;       // 0..1663
    const float* src = (img ? im1 : im2) + b * C_ * 1600;
    _Float16* dst = packed + ((size_t)img * NB + b) * (8 * MPAD * 8);
    float ss = 0.f;
    #pragma unroll
    for (int oct = 0; oct < 8; ++oct) {
        f16x8 h = {};
        if (pos < 1600) {
            #pragma unroll
            for (int j = 0; j < 8; ++j) {
                float v = src[(oct * 8 + j) * 1600 + pos];
                h[j] = (_Float16)v;
                ss += v * v;
            }
        }
        *(f16x8*)&dst[(oct * MPAD + pos) * 8] = h;
    }
    if (img == 1 && pos < 1600) ssqbuf[b * 1600 + pos] = ss;
    if (img == 0 && pos < NL) keys[b * NL + pos] = 0u;
    if (img == 0 && b == 0 && pos == 1600) *counter = 0u;
}

// ===========================================================================
// k_gram: Gt[b][r40][c40][40][40] = sum_c im2[c][m] * im1[c][n], f16,
// BLOCK-TILED output (each 40x40 sub-block contiguous, 3200 B) so box reads
// one plane as a coalesced burst. 8 | 40 so f16x8 stores survive; m,n >=
// 1600 skipped. 128x128 tile, 256 threads, K=64 one shot. Only |i-j| <= 10
// tiles live; 3 dead blocks per batch (i<j) compute invnorm.
// ===========================================================================
__global__ __launch_bounds__(256, 3)
void k_gram(const _Float16* __restrict__ packed, _Float16* __restrict__ G,
            const float* __restrict__ ssqbuf, float* __restrict__ invnorm) {
    const int i = blockIdx.x, j = blockIdx.y, b = blockIdx.z;
    const int tid = threadIdx.x;
    __shared__ __align__(16) _Float16 smem[128 * 136];   // A+B staging / C overlay / norm

    int dd = i - j; if (dd < 0) dd = -dd;
    if (dd > 10) {
        if (i < j) {   // (0,11)->rows 0-9, (0,12)->10-19, (1,12)->20-29
            const int part = (j == 11) ? 0 : ((i == 0) ? 1 : 2);
            const int ly0 = part * 10;
            float* ssq = (float*)smem;          // [20][40]
            float* colsum = ssq + 800;          // [10][40]
            for (int t = tid; t < 800; t += 256)
                ssq[t] = ssqbuf[b * 1600 + ly0 * W_ + t];
            __syncthreads();
            for (int t = tid; t < 10 * W_; t += 256) {
                int yy = t / W_, x = t - yy * W_;
                float s = 0.f;
                #pragma unroll
                for (int r = 0; r < KS; ++r) s += ssq[(yy + r) * W_ + x];
                colsum[t] = s;
            }
            __syncthreads();
            for (int t = tid; t < 10 * HP; t += 256) {
                int ly = t / HP, lx = t - ly * HP;
                float s = 0.f;
                #pragma unroll
                for (int sx = 0; sx < KS; ++sx) s += colsum[ly * W_ + lx + sx];
                invnorm[b * NL + (ly0 + ly) * HP + lx] = 1.f / fmaxf(sqrtf(s), EPSF);
            }
        }
        return;
    }
    const int w = tid >> 6, L = tid & 63, lq = L >> 4, lr = L & 15;

    _Float16 (*As)[128][8] = (_Float16 (*)[128][8])smem;
    _Float16 (*Bs)[128][8] = (_Float16 (*)[128][8])(smem + 8192);

    const _Float16* pa = packed + (size_t)b * (8 * MPAD * 8);
    const _Float16* pb = packed + (size_t)(NB + b) * (8 * MPAD * 8);
    for (int t = tid; t < 1024; t += 256) {
        int oct = t >> 7, m = t & 127;
        *(f16x8*)&As[oct][m][0] = *(const f16x8*)&pa[(oct * MPAD + i * 128 + m) * 8];
        *(f16x8*)&Bs[oct][m][0] = *(const f16x8*)&pb[(oct * MPAD + j * 128 + m) * 8];
    }
    __syncthreads();

    const int mb = (w & 1) * 64, nb = (w >> 1) * 64;
    f16x8 a0[4], a1[4], b0[4], b1[4];
    #pragma unroll
    for (int q = 0; q < 4; ++q) {
        a0[q] = *(const f16x8*)&As[lq][mb + q * 16 + lr][0];
        a1[q] = *(const f16x8*)&As[4 + lq][mb + q * 16 + lr][0];
        b0[q] = *(const f16x8*)&Bs[lq][nb + q * 16 + lr][0];
        b1[q] = *(const f16x8*)&Bs[4 + lq][nb + q * 16 + lr][0];
    }
    f32x4 acc[4][4];
    #pragma unroll
    for (int mi = 0; mi < 4; ++mi)
        #pragma unroll
        for (int ni = 0; ni < 4; ++ni) {
            f32x4 c = {0.f, 0.f, 0.f, 0.f};
            c = __builtin_amdgcn_mfma_f32_16x16x32_f16(a0[mi], b0[ni], c, 0, 0, 0);
            c = __builtin_amdgcn_mfma_f32_16x16x32_f16(a1[mi], b1[ni], c, 0, 0, 0);
            acc[mi][ni] = c;
        }
    __syncthreads();   // frags in regs; safe to overlay C on smem
    // C layout: row (A/m) = quad*4+reg, col (B/n) = lane&15
    #pragma unroll
    for (int mi = 0; mi < 4; ++mi)
        #pragma unroll
        for (int ni = 0; ni < 4; ++ni)
            #pragma unroll
            for (int rg = 0; rg < 4; ++rg)
                smem[(mb + mi * 16 + lq * 4 + rg) * 136 + nb + ni * 16 + lr] =
                    (_Float16)acc[mi][ni][rg];
    __syncthreads();
    _Float16* Gb = G + (size_t)b * GBATCH;
    for (int t = tid; t < 2048; t += 256) {
        int row = t >> 4, seg = t & 15;
        int m = i * 128 + row, n = j * 128 + seg * 8;
        if (m < 1600 && n < 1600) {
            int r = m / 40, mr = m - r * 40;
            int c = n / 40, nc = n - c * 40;
            *(f16x8*)&Gb[(size_t)(r * 40 + c) * GBLK + mr * 40 + nc] =
                *(const f16x8*)&smem[row * 136 + seg * 8];
        }
    }
}

// ===========================================================================
// k_box: R7 structure + fused decode. Per (chunk, dy, b): bulk-stage all
// P+10 planes (<= 64 KB) into LDS once (each plane fetched exactly once),
// register column sums, fused diag 11-tap + max with invnorm folded in,
// csum double-buffered -> 1 barrier per output row. Every block (incl.
// early-outs) bumps the device-scope done-counter; the LAST block decodes
// keys -> float out (coherent atomicMax(p,0) reads). LDS 78 KB -> 2/CU.
// ===========================================================================
__global__ __launch_bounds__(256, 2)
void k_box(const _Float16* __restrict__ G, const float* __restrict__ invnorm,
           unsigned int* __restrict__ keys, float* __restrict__ out,
           unsigned int* __restrict__ counter) {
    __shared__ __align__(16) _Float16 pl_lds[NPLMAX * GBLK];   // 64000 B
    __shared__ float csum2[2 * 1600];                          // 12800 B
    __shared__ float sInv[PCHB * HP];                          //  1200 B
    __shared__ unsigned int lastFlag;
    const int chunk = blockIdx.x;
    const int dy = (int)blockIdx.y - (HP - 1);
    const int b = blockIdx.z;
    const int ady = dy < 0 ? -dy : dy;
    const int rows = HP - ady;
    const int tid = threadIdx.x;

    if (chunk * PCHB < rows) {
        const int pyLo = dy < 0 ? -dy : 0;
        const int py0 = pyLo + chunk * PCHB;
        const int P = min(PCHB, rows - chunk * PCHB);
        const int nPl = P + KS - 1;

        // bulk-load all planes for this chunk into LDS (fetched exactly once)
        const _Float16* Gb = G + (size_t)b * GBATCH + (size_t)(py0 * 41 + dy) * GBLK;
        for (int t = tid; t < nPl * 200; t += 256) {
            int pl = t / 200, e = t - pl * 200;
            *(f16x8*)&pl_lds[pl * GBLK + e * 8] = *(const f16x8*)&Gb[pl * GSTEPT + e * 8];
        }
        for (int t = tid; t < P * HP; t += 256) {
            int i = t / HP, lx = t - i * HP;
            sInv[i * HP + lx] = invnorm[b * NL + (py0 + i + dy) * HP + lx];
        }
        __syncthreads();

        // initial column sums (rows 0..10) from LDS
        float s[8];
        if (tid < 200) {
            #pragma unroll
            for (int j = 0; j < 8; ++j) s[j] = 0.f;
            for (int r = 0; r < KS; ++r) {
                f16x8 q = *(const f16x8*)&pl_lds[r * GBLK + tid * 8];
                #pragma unroll
                for (int j = 0; j < 8; ++j) s[j] += (float)q[j];
            }
        }

        for (int i = 0; i < P; ++i) {
            float* cb = csum2 + (i & 1) * 1600;
            if (tid < 200) {
                if (i > 0) {       // slide: + row i+10, - row i-1 (LDS)
                    f16x8 qa = *(const f16x8*)&pl_lds[(i + 10) * GBLK + tid * 8];
                    f16x8 qs = *(const f16x8*)&pl_lds[(i - 1) * GBLK + tid * 8];
                    #pragma unroll
                    for (int j = 0; j < 8; ++j) s[j] += (float)qa[j] - (float)qs[j];
                }
                float4* c4 = (float4*)(cb + tid * 8);
                c4[0] = make_float4(s[0], s[1], s[2], s[3]);
                c4[1] = make_float4(s[4], s[5], s[6], s[7]);
            }
            __syncthreads();   // cb ready; also fences compute(i-2)'s reads of cb
            // fused diag 11-tap + max: t<240 -> px = t>>3, owns lx = (t&7)+8k
            if (tid < 240) {
                int px = tid >> 3, l = tid & 7;
                const float* cp = cb + px * 40;        // + lx + sr*41 below
                const float* inv = sInv + i * HP;
                float m = NINF;
                #pragma unroll
                for (int k = 0; k < 4; ++k) {
                    int lx = l + 8 * k;
                    if (lx < HP) {
                        const float* cpl = cp + lx;
                        float run = 0.f;
                        #pragma unroll
                        for (int sr = 0; sr < KS; ++sr) run += cpl[sr * 41];
                        m = fmaxf(m, run * inv[lx]);
                    }
                }
                m = fmaxf(m, __shfl_xor(m, 1));
                m = fmaxf(m, __shfl_xor(m, 2));
                m = fmaxf(m, __shfl_xor(m, 4));
                if (l == 0) {
                    unsigned int ub = __float_as_uint(m);
                    unsigned int k2 = (ub & 0x80000000u) ? ~ub : (ub | 0x80000000u);
                    atomicMax(&keys[b * NL + (py0 + i) * HP + px], k2);
                }
            }
            // no trailing barrier: next iteration writes the OTHER csum buffer
        }
    }

    // fused decode: last finished block converts keys -> float output
    __syncthreads();            // drain this block's atomicMax ops
    if (tid == 0) {
        __threadfence();        // release before counter bump
        lastFlag = (atomicAdd(counter, 1u) == (unsigned int)(TOTALB - 1)) ? 1u : 0u;
    }
    __syncthreads();
    if (lastFlag) {
        for (int t = tid; t < NB * NL; t += 256) {
            unsigned int k = atomicMax(&keys[t], 0u);   // coherent read of final max
            unsigned int u = (k & 0x80000000u) ? (k ^ 0x80000000u) : ~k;
            out[t] = __uint_as_float(u);
        }
    }
}

// ===========================================================================
// k_decode: monotone uint keys -> float output (fallback path only)
// ===========================================================================
__global__ __launch_bounds__(256)
void k_decode(const unsigned int* __restrict__ keys, float* __restrict__ out) {
    int i = blockIdx.x * 256 + threadIdx.x;
    if (i < NB * NL) {
        unsigned int k = keys[i];
        unsigned int u = (k & 0x80000000u) ? (k ^ 0x80000000u) : ~k;
        out[i] = __uint_as_float(u);
    }
}

// ===========================================================================
// Fallback path (no big ws): R3 structure (uses PCH=6, MAXPL=16)
// ===========================================================================
__global__ __launch_bounds__(256)
void k_norm_fb(const float* __restrict__ im1, float* __restrict__ invnorm) {
    const int ly = blockIdx.x, b = blockIdx.y;
    const int tid = threadIdx.x;
    __shared__ float colsq[KS * W_];
    __shared__ float colsum[W_];
    const float* base = im1 + b * C_ * H_ * W_;
    for (int i = tid; i < KS * W_; i += 256) {
        int r = i / W_, x = i - r * W_;
        const float* p = base + (ly + r) * W_ + x;
        float s = 0.f;
        #pragma unroll 8
        for (int c = 0; c < C_; ++c) { float v = p[c * H_ * W_]; s += v * v; }
        colsq[i] = s;
    }
    __syncthreads();
    if (tid < W_) {
        float s = 0.f;
        #pragma unroll
        for (int r = 0; r < KS; ++r) s += colsq[r * W_ + tid];
        colsum[tid] = s;
    }
    __syncthreads();
    if (tid < HP) {
        float s = 0.f;
        #pragma unroll
        for (int sx = 0; sx < KS; ++sx) s += colsum[tid + sx];
        invnorm[b * NL + ly * HP + tid] = 1.f / fmaxf(sqrtf(s), EPSF);
    }
}

#define MAXPL 16
__global__ __launch_bounds__(256, 2)
void k_main_fb(const float* __restrict__ im1, const float* __restrict__ im2,
               const float* __restrict__ invnorm, unsigned int* __restrict__ keys) {
    const int chunk = blockIdx.x;
    const int dy = (int)blockIdx.y - (HP - 1);
    const int b = blockIdx.z;
    const int ady = dy < 0 ? -dy : dy;
    const int rows = HP - ady;
    if (chunk * PCH >= rows) return;
    const int pyLo = dy < 0 ? -dy : 0;
    const int py0 = pyLo + chunk * PCH;
    const int P = min(PCH, rows - chunk * PCH);
    const int nPl = P + KS - 1;
    const int tid = threadIdx.x;
    const int w = tid >> 6, L = tid & 63, lq = L >> 4, lr = L & 15;

    __shared__ __align__(16) _Float16 planes[MAXPL][H_ * W_];
    __shared__ __align__(16) float csum[H_ * W_];
    __shared__ __align__(16) _Float16 Astg[8][48][8];
    __shared__ __align__(16) _Float16 Bstg[8][48][8];
    __shared__ float scratch[HP * SCW];
    __shared__ float partials[120];
    __shared__ float sInv[HP];

    const float* im1b = im1 + b * C_ * H_ * W_;
    const float* im2b = im2 + b * C_ * H_ * W_;
    if (tid < 128) {
        int arr = tid >> 6, r = tid & 63;
        int oct = r >> 3, x = 40 + (r & 7);
        f16x8 z = {};
        *(f16x8*)((arr ? Bstg : Astg)[oct][x]) = z;
    }
    for (int p = 0; p < nPl; ++p) {
        const int y = py0 + p;
        for (int t = tid; t < 640; t += 256) {
            int arr = t >= 320;
            int r = arr ? t - 320 : t;
            int oct = r / 40, x = r - oct * 40;
            const float* pc = (arr ? (im1b + (y + dy) * W_) : (im2b + y * W_))
                              + oct * 8 * H_ * W_ + x;
            f16x8 h;
            #pragma unroll
            for (int j = 0; j < 8; ++j) h[j] = (_Float16)pc[j * H_ * W_];
            *(f16x8*)((arr ? Bstg : Astg)[oct][x]) = h;
        }
        __syncthreads();
        for (int t = w; t < 9; t += 4) {
            int mt = t / 3, nt = t - 3 * mt;
            f16x8 a0 = *(const f16x8*)(Astg[lq][mt * 16 + lr]);
            f16x8 b0 = *(const f16x8*)(Bstg[lq][nt * 16 + lr]);
            f16x8 a1 = *(const f16x8*)(Astg[4 + lq][mt * 16 + lr]);
            f16x8 b1 = *(const f16x8*)(Bstg[4 + lq][nt * 16 + lr]);
            f32x4 acc = {0.f, 0.f, 0.f, 0.f};
            acc = __builtin_amdgcn_mfma_f32_16x16x32_f16(a0, b0, acc, 0, 0, 0);
            acc = __builtin_amdgcn_mfma_f32_16x16x32_f16(a1, b1, acc, 0, 0, 0);
            int x1 = nt * 16 + lr;
            if (x1 < W_) {
                int x2b = mt * 16 + lq * 4;
                #pragma unroll
                for (int rg = 0; rg < 4; ++rg) {
                    int x2 = x2b + rg;
                    if (x2 < W_) planes[p][x2 * W_ + x1] = (_Float16)acc[rg];
                }
            }
        }
        __syncthreads();
    }
    for (int i = 0; i < P; ++i) {
        const int py = py0 + i, ly = py + dy;
        if (tid < 200) {
            float4* c4 = (float4*)(csum + tid * 8);
            if (i == 0) {
                float s[8] = {0.f,0.f,0.f,0.f,0.f,0.f,0.f,0.f};
                #pragma unroll
                for (int r = 0; r < KS; ++r) {
                    f16x8 q = *(const f16x8*)(planes[r] + tid * 8);
                    #pragma unroll
                    for (int j = 0; j < 8; ++j) s[j] += (float)q[j];
                }
                c4[0] = make_float4(s[0], s[1], s[2], s[3]);
                c4[1] = make_float4(s[4], s[5], s[6], s[7]);
            } else {
                f16x8 qa = *(const f16x8*)(planes[i + 10] + tid * 8);
                f16x8 qs = *(const f16x8*)(planes[i - 1] + tid * 8);
                float4 v0 = c4[0], v1 = c4[1];
                v0.x += (float)qa[0] - (float)qs[0]; v0.y += (float)qa[1] - (float)qs[1];
                v0.z += (float)qa[2] - (float)qs[2]; v0.w += (float)qa[3] - (float)qs[3];
                v1.x += (float)qa[4] - (float)qs[4]; v1.y += (float)qa[5] - (float)qs[5];
                v1.z += (float)qa[6] - (float)qs[6]; v1.w += (float)qa[7] - (float)qs[7];
                c4[0] = v0; c4[1] = v1;
            }
        } else if (tid >= 224 && tid < 224 + HP) {
            sInv[tid - 224] = invnorm[b * NL + ly * HP + (tid - 224)];
        }
        __syncthreads();
        for (int t = tid; t < 5 * ND; t += 256) {
            int pg = t / ND, dxI = t - ND * pg;
            int dx = dxI - (HP - 1), pxb = 6 * pg;
            #pragma unroll
            for (int u = 0; u < 6; ++u) scratch[(pxb + u) * SCW + dxI] = NINF;
            int u0 = max(0, -dx - pxb), u1 = min(5, (HP - 1) - dx - pxb);
            if (u0 <= u1) {
                const float* cp = csum + dx;
                float run = 0.f;
                #pragma unroll
                for (int sr = 0; sr < KS; ++sr) run += cp[(pxb + u0 + sr) * (W_ + 1)];
                int u = u0;
                for (;;) {
                    scratch[(pxb + u) * SCW + dxI] = run * sInv[pxb + u + dx];
                    if (++u > u1) break;
                    run += cp[(pxb + u + 10) * (W_ + 1)] - cp[(pxb + u - 1) * (W_ + 1)];
                }
            }
        }
        __syncthreads();
        if (tid < 120) {
            int px = tid >> 2, q = tid & 3;
            float m = NINF;
            int d0 = q * 15, d1 = min(d0 + 15, ND);
            for (int d = d0; d < d1; ++d) m = fmaxf(m, scratch[px * SCW + d]);
            partials[tid] = m;
        }
        __syncthreads();
        if (tid < HP) {
            float m = fmaxf(fmaxf(partials[tid * 4], partials[tid * 4 + 1]),
                            fmaxf(partials[tid * 4 + 2], partials[tid * 4 + 3]));
            unsigned int ub = __float_as_uint(m);
            unsigned int k = (ub & 0x80000000u) ? ~ub : (ub | 0x80000000u);
            atomicMax(&keys[b * NL + py * HP + tid], k);
        }
        __syncthreads();
    }
}

extern "C" void kernel_launch(void* const* d_in, const int* in_sizes, int n_in,
                              void* d_out, int out_size, void* d_ws, size_t ws_size,
                              hipStream_t stream) {
    const float* im1 = (const float*)d_in[0];
    const float* im2 = (const float*)d_in[1];
    unsigned int* keys = (unsigned int*)d_ws;                      // 14400 B @ 0
    float* invnorm = (float*)((char*)d_ws + 14400);                // 14400 B
    float* ssqbuf  = (float*)((char*)d_ws + 28800);                // 25600 B
    unsigned int* counter = (unsigned int*)((char*)d_ws + 54400);  // 4 B
    const size_t packedOff = 65536;
    const size_t packedBytes = (size_t)2 * NB * 8 * MPAD * 8 * 2;  // 1,703,936
    const size_t gOff = packedOff + packedBytes;
    const size_t gBytes = (size_t)NB * GBATCH * 2;                 // 20,480,000
    const size_t needed = gOff + gBytes;

    if (ws_size >= needed) {
        _Float16* packed = (_Float16*)((char*)d_ws + packedOff);
        _Float16* G = (_Float16*)((char*)d_ws + gOff);
        k_pack<<<dim3(13, NB, 2), 128, 0, stream>>>(im2, im1, packed, ssqbuf, keys, counter);
        k_gram<<<dim3(13, 13, NB), 256, 0, stream>>>(packed, G, ssqbuf, invnorm);
        k_box<<<dim3(NCHB, ND, NB), 256, 0, stream>>>(G, invnorm, keys, (float*)d_out, counter);
    } else {
        hipMemsetAsync(d_ws, 0, NB * NL * sizeof(unsigned int), stream);
        k_norm_fb<<<dim3(HP, NB), 256, 0, stream>>>(im1, invnorm);
        k_main_fb<<<dim3(5, ND, NB), 256, 0, stream>>>(im1, im2, invnorm, keys);
        k_decode<<<(NB * NL + 255) / 256, 256, 0, stream>>>(keys, (float*)d_out);
    }
}

// Round 11
// 92.203 us; speedup vs baseline: 1.1134x; 1.1134x over previous
//
#include <hip/hip_runtime.h>

#define C_    64
#define H_    40
#define W_    40
#define KS    11
#define HP    30          // H_ - KS + 1
#define NB    4
#define NL    900         // HP*HP
#define ND    59          // 2*(HP-1)+1
#define EPSF  1e-4f
#define PCH   6           // output rows per chunk (fallback path)
#define PCHB  10          // output rows per chunk (main box path)
#define NCHB  3           // ceil(HP/PCHB)
#define NPLMAX (PCHB + KS - 1)   // 20 planes resident in LDS
#define SCW   65          // fallback scratch row stride (odd -> conflict-free)
#define NINF  -3.4e38f
#define MPAD  1664        // 13*128, padded M=N (packed staging only)
#define GBLK  1600        // elements per 40x40 G block (f16)
#define GBATCH (1600 * 1600)   // elements of Gt per batch
#define GSTEPT 65600      // 41*1600: plane-to-plane step along the dy diagonal

typedef _Float16 f16x8 __attribute__((ext_vector_type(8)));
typedef float    f32x4 __attribute__((ext_vector_type(4)));

// ===========================================================================
// k_pack: fp32 images -> f16 octet-packed packed[img][b][oct][MPAD][8].
//         grid (13, NB, 2) x 128 threads; fully coalesced. img==1 also writes
//         per-pixel channel sum-of-squares; img==0 zeroes the keys buffer.
// ===========================================================================
__global__ __launch_bounds__(128)
void k_pack(const float* __restrict__ im2, const float* __restrict__ im1,
            _Float16* __restrict__ packed, float* __restrict__ ssqbuf,
            unsigned int* __restrict__ keys) {
    const int blk = blockIdx.x, b = blockIdx.y, img = blockIdx.z;
    const int pos = blk * 128 + threadIdx.x;       // 0..1663
    const float* src = (img ? im1 : im2) + b * C_ * 1600;
    _Float16* dst = packed + ((size_t)img * NB + b) * (8 * MPAD * 8);
    float ss = 0.f;
    #pragma unroll
    for (int oct = 0; oct < 8; ++oct) {
        f16x8 h = {};
        if (pos < 1600) {
            #pragma unroll
            for (int j = 0; j < 8; ++j) {
                float v = src[(oct * 8 + j) * 1600 + pos];
                h[j] = (_Float16)v;
                ss += v * v;
            }
        }
        *(f16x8*)&dst[(oct * MPAD + pos) * 8] = h;
    }
    if (img == 1 && pos < 1600) ssqbuf[b * 1600 + pos] = ss;
    if (img == 0 && pos < NL) keys[b * NL + pos] = 0u;
}

// ===========================================================================
// k_gram: Gt[b][r40][c40][40][40] = sum_c im2[c][m] * im1[c][n], f16,
// BLOCK-TILED output: each 40x40 (r,c) sub-block contiguous (3200 B) so the
// box kernel reads one plane as a single coalesced burst. 8-elem segments
// never cross a 40-boundary (8 | 40) so f16x8 stores survive; m,n >= 1600
// (pad region) skipped. 128x128 tile per block, 256 threads, K=64 one shot.
// Only the |i-j| <= 10 tile band is live. 3 dead blocks per batch (i<j)
// compute invnorm (separable 11x11 box of ssq), 10 output rows each.
// ===========================================================================
__global__ __launch_bounds__(256, 3)
void k_gram(const _Float16* __restrict__ packed, _Float16* __restrict__ G,
            const float* __restrict__ ssqbuf, float* __restrict__ invnorm) {
    const int i = blockIdx.x, j = blockIdx.y, b = blockIdx.z;
    const int tid = threadIdx.x;
    __shared__ __align__(16) _Float16 smem[128 * 136];   // A+B staging / C overlay / norm

    int dd = i - j; if (dd < 0) dd = -dd;
    if (dd > 10) {
        if (i < j) {   // (0,11)->rows 0-9, (0,12)->10-19, (1,12)->20-29
            const int part = (j == 11) ? 0 : ((i == 0) ? 1 : 2);
            const int ly0 = part * 10;
            float* ssq = (float*)smem;          // [20][40]
            float* colsum = ssq + 800;          // [10][40]
            for (int t = tid; t < 800; t += 256)
                ssq[t] = ssqbuf[b * 1600 + ly0 * W_ + t];
            __syncthreads();
            for (int t = tid; t < 10 * W_; t += 256) {
                int yy = t / W_, x = t - yy * W_;
                float s = 0.f;
                #pragma unroll
                for (int r = 0; r < KS; ++r) s += ssq[(yy + r) * W_ + x];
                colsum[t] = s;
            }
            __syncthreads();
            for (int t = tid; t < 10 * HP; t += 256) {
                int ly = t / HP, lx = t - ly * HP;
                float s = 0.f;
                #pragma unroll
                for (int sx = 0; sx < KS; ++sx) s += colsum[ly * W_ + lx + sx];
                invnorm[b * NL + (ly0 + ly) * HP + lx] = 1.f / fmaxf(sqrtf(s), EPSF);
            }
        }
        return;
    }
    const int w = tid >> 6, L = tid & 63, lq = L >> 4, lr = L & 15;

    _Float16 (*As)[128][8] = (_Float16 (*)[128][8])smem;
    _Float16 (*Bs)[128][8] = (_Float16 (*)[128][8])(smem + 8192);

    const _Float16* pa = packed + (size_t)b * (8 * MPAD * 8);
    const _Float16* pb = packed + (size_t)(NB + b) * (8 * MPAD * 8);
    for (int t = tid; t < 1024; t += 256) {
        int oct = t >> 7, m = t & 127;
        *(f16x8*)&As[oct][m][0] = *(const f16x8*)&pa[(oct * MPAD + i * 128 + m) * 8];
        *(f16x8*)&Bs[oct][m][0] = *(const f16x8*)&pb[(oct * MPAD + j * 128 + m) * 8];
    }
    __syncthreads();

    const int mb = (w & 1) * 64, nb = (w >> 1) * 64;
    f16x8 a0[4], a1[4], b0[4], b1[4];
    #pragma unroll
    for (int q = 0; q < 4; ++q) {
        a0[q] = *(const f16x8*)&As[lq][mb + q * 16 + lr][0];
        a1[q] = *(const f16x8*)&As[4 + lq][mb + q * 16 + lr][0];
        b0[q] = *(const f16x8*)&Bs[lq][nb + q * 16 + lr][0];
        b1[q] = *(const f16x8*)&Bs[4 + lq][nb + q * 16 + lr][0];
    }
    f32x4 acc[4][4];
    #pragma unroll
    for (int mi = 0; mi < 4; ++mi)
        #pragma unroll
        for (int ni = 0; ni < 4; ++ni) {
            f32x4 c = {0.f, 0.f, 0.f, 0.f};
            c = __builtin_amdgcn_mfma_f32_16x16x32_f16(a0[mi], b0[ni], c, 0, 0, 0);
            c = __builtin_amdgcn_mfma_f32_16x16x32_f16(a1[mi], b1[ni], c, 0, 0, 0);
            acc[mi][ni] = c;
        }
    __syncthreads();   // frags in regs; safe to overlay C on smem
    // C layout: row (A/m) = quad*4+reg, col (B/n) = lane&15
    #pragma unroll
    for (int mi = 0; mi < 4; ++mi)
        #pragma unroll
        for (int ni = 0; ni < 4; ++ni)
            #pragma unroll
            for (int rg = 0; rg < 4; ++rg)
                smem[(mb + mi * 16 + lq * 4 + rg) * 136 + nb + ni * 16 + lr] =
                    (_Float16)acc[mi][ni][rg];
    __syncthreads();
    _Float16* Gb = G + (size_t)b * GBATCH;
    for (int t = tid; t < 2048; t += 256) {
        int row = t >> 4, seg = t & 15;
        int m = i * 128 + row, n = j * 128 + seg * 8;
        if (m < 1600 && n < 1600) {
            int r = m / 40, mr = m - r * 40;
            int c = n / 40, nc = n - c * 40;
            *(f16x8*)&Gb[(size_t)(r * 40 + c) * GBLK + mr * 40 + nc] =
                *(const f16x8*)&smem[row * 136 + seg * 8];
        }
    }
}

// ===========================================================================
// k_box: per (chunk, dy, b). BULK-LDS-STAGED: all P+10 planes for the chunk
// (<= 20 x 3.2 KB = 64 KB) are streamed into LDS once at block start — each
// G plane fetched from HBM exactly once, latency hidden by the bulk burst.
// Sliding column sums then read LDS. Diag 11-tap + max are FUSED into one
// phase (run computed per (px,lx) directly from csum at addr (px+s)*41 +
// lx-px; 2-way banked = free), and csum is double-buffered -> exactly ONE
// barrier per output row. fmax reassociation only (bit-exact).
// LDS 78 KB -> 2 blocks/CU (grid is ~1.8 live blocks/CU anyway).
// ===========================================================================
__global__ __launch_bounds__(256, 2)
void k_box(const _Float16* __restrict__ G, const float* __restrict__ invnorm,
           unsigned int* __restrict__ keys) {
    __shared__ __align__(16) _Float16 pl_lds[NPLMAX * GBLK];   // 64000 B
    __shared__ float csum2[2 * 1600];                          // 12800 B
    __shared__ float sInv[PCHB * HP];                          //  1200 B
    const int chunk = blockIdx.x;
    const int dy = (int)blockIdx.y - (HP - 1);
    const int b = blockIdx.z;
    const int ady = dy < 0 ? -dy : dy;
    const int rows = HP - ady;
    if (chunk * PCHB >= rows) return;
    const int pyLo = dy < 0 ? -dy : 0;
    const int py0 = pyLo + chunk * PCHB;
    const int P = min(PCHB, rows - chunk * PCHB);
    const int nPl = P + KS - 1;
    const int tid = threadIdx.x;

    // bulk-load all planes for this chunk into LDS (each fetched exactly once)
    const _Float16* Gb = G + (size_t)b * GBATCH + (size_t)(py0 * 41 + dy) * GBLK;
    for (int t = tid; t < nPl * 200; t += 256) {
        int pl = t / 200, e = t - pl * 200;
        *(f16x8*)&pl_lds[pl * GBLK + e * 8] = *(const f16x8*)&Gb[pl * GSTEPT + e * 8];
    }
    for (int t = tid; t < P * HP; t += 256) {
        int i = t / HP, lx = t - i * HP;
        sInv[i * HP + lx] = invnorm[b * NL + (py0 + i + dy) * HP + lx];
    }
    __syncthreads();

    // initial column sums (rows 0..10) from LDS
    float s[8];
    if (tid < 200) {
        #pragma unroll
        for (int j = 0; j < 8; ++j) s[j] = 0.f;
        for (int r = 0; r < KS; ++r) {
            f16x8 q = *(const f16x8*)&pl_lds[r * GBLK + tid * 8];
            #pragma unroll
            for (int j = 0; j < 8; ++j) s[j] += (float)q[j];
        }
    }

    for (int i = 0; i < P; ++i) {
        float* cb = csum2 + (i & 1) * 1600;
        if (tid < 200) {
            if (i > 0) {       // slide: + row i+10, - row i-1 (LDS)
                f16x8 qa = *(const f16x8*)&pl_lds[(i + 10) * GBLK + tid * 8];
                f16x8 qs = *(const f16x8*)&pl_lds[(i - 1) * GBLK + tid * 8];
                #pragma unroll
                for (int j = 0; j < 8; ++j) s[j] += (float)qa[j] - (float)qs[j];
            }
            float4* c4 = (float4*)(cb + tid * 8);
            c4[0] = make_float4(s[0], s[1], s[2], s[3]);
            c4[1] = make_float4(s[4], s[5], s[6], s[7]);
        }
        __syncthreads();   // cb ready; also fences compute(i-2)'s reads of cb
        // fused diag 11-tap + max: thread t<240 -> px = t>>3, owns lx = (t&7)+8k
        if (tid < 240) {
            int px = tid >> 3, l = tid & 7;
            const float* cp = cb + px * 40;        // + lx + sr*41 below
            const float* inv = sInv + i * HP;
            float m = NINF;
            #pragma unroll
            for (int k = 0; k < 4; ++k) {
                int lx = l + 8 * k;
                if (lx < HP) {
                    const float* cpl = cp + lx;
                    float run = 0.f;
                    #pragma unroll
                    for (int sr = 0; sr < KS; ++sr) run += cpl[sr * 41];
                    m = fmaxf(m, run * inv[lx]);
                }
            }
            m = fmaxf(m, __shfl_xor(m, 1));
            m = fmaxf(m, __shfl_xor(m, 2));
            m = fmaxf(m, __shfl_xor(m, 4));
            if (l == 0) {
                unsigned int ub = __float_as_uint(m);
                unsigned int k2 = (ub & 0x80000000u) ? ~ub : (ub | 0x80000000u);
                atomicMax(&keys[b * NL + (py0 + i) * HP + px], k2);
            }
        }
        // no trailing barrier: next iteration writes the OTHER csum buffer;
        // this buffer's next write is fenced by the next iteration's barrier.
    }
}

// ===========================================================================
// k_decode: monotone uint keys -> float output
// ===========================================================================
__global__ __launch_bounds__(256)
void k_decode(const unsigned int* __restrict__ keys, float* __restrict__ out) {
    int i = blockIdx.x * 256 + threadIdx.x;
    if (i < NB * NL) {
        unsigned int k = keys[i];
        unsigned int u = (k & 0x80000000u) ? (k ^ 0x80000000u) : ~k;
        out[i] = __uint_as_float(u);
    }
}

// ===========================================================================
// Fallback path (no big ws): R3 structure (uses PCH=6, MAXPL=16)
// ===========================================================================
__global__ __launch_bounds__(256)
void k_norm_fb(const float* __restrict__ im1, float* __restrict__ invnorm) {
    const int ly = blockIdx.x, b = blockIdx.y;
    const int tid = threadIdx.x;
    __shared__ float colsq[KS * W_];
    __shared__ float colsum[W_];
    const float* base = im1 + b * C_ * H_ * W_;
    for (int i = tid; i < KS * W_; i += 256) {
        int r = i / W_, x = i - r * W_;
        const float* p = base + (ly + r) * W_ + x;
        float s = 0.f;
        #pragma unroll 8
        for (int c = 0; c < C_; ++c) { float v = p[c * H_ * W_]; s += v * v; }
        colsq[i] = s;
    }
    __syncthreads();
    if (tid < W_) {
        float s = 0.f;
        #pragma unroll
        for (int r = 0; r < KS; ++r) s += colsq[r * W_ + tid];
        colsum[tid] = s;
    }
    __syncthreads();
    if (tid < HP) {
        float s = 0.f;
        #pragma unroll
        for (int sx = 0; sx < KS; ++sx) s += colsum[tid + sx];
        invnorm[b * NL + ly * HP + tid] = 1.f / fmaxf(sqrtf(s), EPSF);
    }
}

#define MAXPL 16
__global__ __launch_bounds__(256, 2)
void k_main_fb(const float* __restrict__ im1, const float* __restrict__ im2,
               const float* __restrict__ invnorm, unsigned int* __restrict__ keys) {
    const int chunk = blockIdx.x;
    const int dy = (int)blockIdx.y - (HP - 1);
    const int b = blockIdx.z;
    const int ady = dy < 0 ? -dy : dy;
    const int rows = HP - ady;
    if (chunk * PCH >= rows) return;
    const int pyLo = dy < 0 ? -dy : 0;
    const int py0 = pyLo + chunk * PCH;
    const int P = min(PCH, rows - chunk * PCH);
    const int nPl = P + KS - 1;
    const int tid = threadIdx.x;
    const int w = tid >> 6, L = tid & 63, lq = L >> 4, lr = L & 15;

    __shared__ __align__(16) _Float16 planes[MAXPL][H_ * W_];
    __shared__ __align__(16) float csum[H_ * W_];
    __shared__ __align__(16) _Float16 Astg[8][48][8];
    __shared__ __align__(16) _Float16 Bstg[8][48][8];
    __shared__ float scratch[HP * SCW];
    __shared__ float partials[120];
    __shared__ float sInv[HP];

    const float* im1b = im1 + b * C_ * H_ * W_;
    const float* im2b = im2 + b * C_ * H_ * W_;
    if (tid < 128) {
        int arr = tid >> 6, r = tid & 63;
        int oct = r >> 3, x = 40 + (r & 7);
        f16x8 z = {};
        *(f16x8*)((arr ? Bstg : Astg)[oct][x]) = z;
    }
    for (int p = 0; p < nPl; ++p) {
        const int y = py0 + p;
        for (int t = tid; t < 640; t += 256) {
            int arr = t >= 320;
            int r = arr ? t - 320 : t;
            int oct = r / 40, x = r - oct * 40;
            const float* pc = (arr ? (im1b + (y + dy) * W_) : (im2b + y * W_))
                              + oct * 8 * H_ * W_ + x;
            f16x8 h;
            #pragma unroll
            for (int j = 0; j < 8; ++j) h[j] = (_Float16)pc[j * H_ * W_];
            *(f16x8*)((arr ? Bstg : Astg)[oct][x]) = h;
        }
        __syncthreads();
        for (int t = w; t < 9; t += 4) {
            int mt = t / 3, nt = t - 3 * mt;
            f16x8 a0 = *(const f16x8*)(Astg[lq][mt * 16 + lr]);
            f16x8 b0 = *(const f16x8*)(Bstg[lq][nt * 16 + lr]);
            f16x8 a1 = *(const f16x8*)(Astg[4 + lq][mt * 16 + lr]);
            f16x8 b1 = *(const f16x8*)(Bstg[4 + lq][nt * 16 + lr]);
            f32x4 acc = {0.f, 0.f, 0.f, 0.f};
            acc = __builtin_amdgcn_mfma_f32_16x16x32_f16(a0, b0, acc, 0, 0, 0);
            acc = __builtin_amdgcn_mfma_f32_16x16x32_f16(a1, b1, acc, 0, 0, 0);
            int x1 = nt * 16 + lr;
            if (x1 < W_) {
                int x2b = mt * 16 + lq * 4;
                #pragma unroll
                for (int rg = 0; rg < 4; ++rg) {
                    int x2 = x2b + rg;
                    if (x2 < W_) planes[p][x2 * W_ + x1] = (_Float16)acc[rg];
                }
            }
        }
        __syncthreads();
    }
    for (int i = 0; i < P; ++i) {
        const int py = py0 + i, ly = py + dy;
        if (tid < 200) {
            float4* c4 = (float4*)(csum + tid * 8);
            if (i == 0) {
                float s[8] = {0.f,0.f,0.f,0.f,0.f,0.f,0.f,0.f};
                #pragma unroll
                for (int r = 0; r < KS; ++r) {
                    f16x8 q = *(const f16x8*)(planes[r] + tid * 8);
                    #pragma unroll
                    for (int j = 0; j < 8; ++j) s[j] += (float)q[j];
                }
                c4[0] = make_float4(s[0], s[1], s[2], s[3]);
                c4[1] = make_float4(s[4], s[5], s[6], s[7]);
            } else {
                f16x8 qa = *(const f16x8*)(planes[i + 10] + tid * 8);
                f16x8 qs = *(const f16x8*)(planes[i - 1] + tid * 8);
                float4 v0 = c4[0], v1 = c4[1];
                v0.x += (float)qa[0] - (float)qs[0]; v0.y += (float)qa[1] - (float)qs[1];
                v0.z += (float)qa[2] - (float)qs[2]; v0.w += (float)qa[3] - (float)qs[3];
                v1.x += (float)qa[4] - (float)qs[4]; v1.y += (float)qa[5] - (float)qs[5];
                v1.z += (float)qa[6] - (float)qs[6]; v1.w += (float)qa[7] - (float)qs[7];
                c4[0] = v0; c4[1] = v1;
            }
        } else if (tid >= 224 && tid < 224 + HP) {
            sInv[tid - 224] = invnorm[b * NL + ly * HP + (tid - 224)];
        }
        __syncthreads();
        for (int t = tid; t < 5 * ND; t += 256) {
            int pg = t / ND, dxI = t - ND * pg;
            int dx = dxI - (HP - 1), pxb = 6 * pg;
            #pragma unroll
            for (int u = 0; u < 6; ++u) scratch[(pxb + u) * SCW + dxI] = NINF;
            int u0 = max(0, -dx - pxb), u1 = min(5, (HP - 1) - dx - pxb);
            if (u0 <= u1) {
                const float* cp = csum + dx;
                float run = 0.f;
                #pragma unroll
                for (int sr = 0; sr < KS; ++sr) run += cp[(pxb + u0 + sr) * (W_ + 1)];
                int u = u0;
                for (;;) {
                    scratch[(pxb + u) * SCW + dxI] = run * sInv[pxb + u + dx];
                    if (++u > u1) break;
                    run += cp[(pxb + u + 10) * (W_ + 1)] - cp[(pxb + u - 1) * (W_ + 1)];
                }
            }
        }
        __syncthreads();
        if (tid < 120) {
            int px = tid >> 2, q = tid & 3;
            float m = NINF;
            int d0 = q * 15, d1 = min(d0 + 15, ND);
            for (int d = d0; d < d1; ++d) m = fmaxf(m, scratch[px * SCW + d]);
            partials[tid] = m;
        }
        __syncthreads();
        if (tid < HP) {
            float m = fmaxf(fmaxf(partials[tid * 4], partials[tid * 4 + 1]),
                            fmaxf(partials[tid * 4 + 2], partials[tid * 4 + 3]));
            unsigned int ub = __float_as_uint(m);
            unsigned int k = (ub & 0x80000000u) ? ~ub : (ub | 0x80000000u);
            atomicMax(&keys[b * NL + py * HP + tid], k);
        }
        __syncthreads();
    }
}

extern "C" void kernel_launch(void* const* d_in, const int* in_sizes, int n_in,
                              void* d_out, int out_size, void* d_ws, size_t ws_size,
                              hipStream_t stream) {
    const float* im1 = (const float*)d_in[0];
    const float* im2 = (const float*)d_in[1];
    unsigned int* keys = (unsigned int*)d_ws;                 // 14400 B @ 0
    float* invnorm = (float*)((char*)d_ws + 14400);           // 14400 B
    float* ssqbuf  = (float*)((char*)d_ws + 28800);           // 25600 B
    const size_t packedOff = 65536;
    const size_t packedBytes = (size_t)2 * NB * 8 * MPAD * 8 * 2;   // 1,703,936
    const size_t gOff = packedOff + packedBytes;
    const size_t gBytes = (size_t)NB * GBATCH * 2;                   // 20,480,000
    const size_t needed = gOff + gBytes;

    if (ws_size >= needed) {
        _Float16* packed = (_Float16*)((char*)d_ws + packedOff);
        _Float16* G = (_Float16*)((char*)d_ws + gOff);
        k_pack<<<dim3(13, NB, 2), 128, 0, stream>>>(im2, im1, packed, ssqbuf, keys);
        k_gram<<<dim3(13, 13, NB), 256, 0, stream>>>(packed, G, ssqbuf, invnorm);
        k_box<<<dim3(NCHB, ND, NB), 256, 0, stream>>>(G, invnorm, keys);
    } else {
        hipMemsetAsync(d_ws, 0, NB * NL * sizeof(unsigned int), stream);
        k_norm_fb<<<dim3(HP, NB), 256, 0, stream>>>(im1, invnorm);
        k_main_fb<<<dim3(5, ND, NB), 256, 0, stream>>>(im1, im2, invnorm, keys);
    }
    k_decode<<<(NB * NL + 255) / 256, 256, 0, stream>>>(keys, (float*)d_out);
}